// Round 5
// baseline (489.683 us; speedup 1.0000x reference)
//
#include <hip/hip_runtime.h>
#include <math.h>

// Qwen3.5 TopK Router, MI355X. fp64-accumulated GEMM for exact index ordering.
// logits = X(T,D) @ W(E,D)^T ; softmax over E; top-8 + renormalize.
// Out layout (all fp32): [T*E softmax-probs | T*K weights | T*K indices-as-float]
//
// R5 changes vs R4 (329 us, VALUBusy 52%, dfma only ~1/3 of VALU time):
//  - fp64 staged in LDS: f32->f64 convert ONCE per element at staging
//    (20 cvt/thread/tile) instead of 12 cvt per kk in the inner loop.
//    Inner loop = ds_read_b128 (immediate offsets) + dfma only.
//  - BM=32, 256-thread blocks, tile 2 tokens x 8 experts, grid 512 =
//    2 INDEPENDENT blocks/CU (own barriers; one computes while the other
//    stages). R4's intra-block split-K shared one barrier -> dependent waves.
//  - B stored interleaved: addr(k,e) = k*128 + ((e&7)>>1)*32 + (e>>3)*2 + (e&1)
//    doubles, so each b128 read is 16 lanes x 16B contiguous (2-way, free).
//    Read r yields experts tx*8+2r, tx*8+2r+1.

constexpr int T = 16384;
constexpr int D = 2048;
constexpr int E = 128;
constexpr int K = 8;

constexpr int BM = 32;   // tokens per block
constexpr int BK = 32;   // k-chunk

__global__ __launch_bounds__(256, 2)
void router_fused(const float* __restrict__ X,
                  const float* __restrict__ W,
                  float* __restrict__ out)
{
    __shared__ double As[BK * BM];     // [k][token]            8 KB
    __shared__ double Bs[BK * E];      // interleaved, see top  32 KB

    const int tid = threadIdx.x;
    const int tx = tid & 15;           // expert group 0..15 (8 experts each)
    const int ty = tid >> 4;           // token group 0..15 (2 tokens each)
    const long t0 = (long)blockIdx.x * BM;

    double acc[2][8];
#pragma unroll
    for (int i = 0; i < 2; ++i)
#pragma unroll
        for (int j = 0; j < 8; ++j) acc[i][j] = 0.0;

    // A staging: 32 tok x 32 k = 256 float4; one per thread
    const int a_tok = tid >> 3;            // 0..31
    const int a_k4  = (tid & 7) << 2;      // 0,4,...,28
    // B staging: 128 e x 8 k-float4 = 1024 float4; four per thread, contiguous 64B
    const int b_e   = tid >> 1;            // 0..127
    const int b_kb  = (tid & 1) << 4;      // 0 or 16
    const int b_pos = ((b_e & 7) >> 1) * 32 + ((b_e >> 3) << 1) + (b_e & 1);

    const float* Xp = X + (t0 + a_tok) * D + a_k4;
    const float* Wp = W + (long)b_e * D + b_kb;

    // prologue: load tile 0
    float4 xa  = *(const float4*)(Xp);
    float4 wb0 = *(const float4*)(Wp);
    float4 wb1 = *(const float4*)(Wp + 4);
    float4 wb2 = *(const float4*)(Wp + 8);
    float4 wb3 = *(const float4*)(Wp + 12);

    for (int k0 = 0; k0 < D; k0 += BK) {
        __syncthreads();   // previous tile fully consumed
        {
            As[(a_k4+0)*BM + a_tok] = (double)xa.x;
            As[(a_k4+1)*BM + a_tok] = (double)xa.y;
            As[(a_k4+2)*BM + a_tok] = (double)xa.z;
            As[(a_k4+3)*BM + a_tok] = (double)xa.w;
            const float4 wb[4] = {wb0, wb1, wb2, wb3};
#pragma unroll
            for (int i = 0; i < 4; ++i) {
                const int kb = b_kb + (i << 2);
                Bs[(kb+0)*E + b_pos] = (double)wb[i].x;
                Bs[(kb+1)*E + b_pos] = (double)wb[i].y;
                Bs[(kb+2)*E + b_pos] = (double)wb[i].z;
                Bs[(kb+3)*E + b_pos] = (double)wb[i].w;
            }
        }
        __syncthreads();

        // prefetch next tile while computing this one
        const int kn = k0 + BK;
        if (kn < D) {
            xa  = *(const float4*)(Xp + kn);
            wb0 = *(const float4*)(Wp + kn);
            wb1 = *(const float4*)(Wp + kn + 4);
            wb2 = *(const float4*)(Wp + kn + 8);
            wb3 = *(const float4*)(Wp + kn + 12);
        }

#pragma unroll
        for (int kk = 0; kk < BK; ++kk) {
            const double2 a01 = *(const double2*)&As[kk*BM + (ty << 1)];
            const double2 b0  = *(const double2*)&Bs[kk*E +  0 + (tx << 1)];
            const double2 b1  = *(const double2*)&Bs[kk*E + 32 + (tx << 1)];
            const double2 b2  = *(const double2*)&Bs[kk*E + 64 + (tx << 1)];
            const double2 b3  = *(const double2*)&Bs[kk*E + 96 + (tx << 1)];
            const double a[2] = {a01.x, a01.y};
            const double b[8] = {b0.x, b0.y, b1.x, b1.y, b2.x, b2.y, b3.x, b3.y};
#pragma unroll
            for (int i = 0; i < 2; ++i)
#pragma unroll
                for (int j = 0; j < 8; ++j)
                    acc[i][j] = fma(a[i], b[j], acc[i][j]);
        }
    }

    float* outL  = out;
    float* outWt = out + (long)T * E;
    float* outId = outWt + (long)T * K;

    // epilogue: each token row = 16 lanes (same ty, all tx) of one wave
    for (int i = 0; i < 2; ++i) {
        const long t = t0 + (ty << 1) + i;

        double m = acc[i][0];
#pragma unroll
        for (int j = 1; j < 8; ++j) m = fmax(m, acc[i][j]);
#pragma unroll
        for (int mask = 1; mask <= 8; mask <<= 1)
            m = fmax(m, __shfl_xor(m, mask, 64));

        float e[8]; float s = 0.f;
#pragma unroll
        for (int j = 0; j < 8; ++j) { e[j] = __expf((float)(acc[i][j] - m)); s += e[j]; }
#pragma unroll
        for (int mask = 1; mask <= 8; mask <<= 1)
            s += __shfl_xor(s, mask, 64);
        const float inv = 1.f / s;

        float p[8];
#pragma unroll
        for (int j = 0; j < 8; ++j) p[j] = e[j] * inv;

        float4 st0 = {p[0], p[1], p[2], p[3]};
        float4 st1 = {p[4], p[5], p[6], p[7]};
        *(float4*)&outL[t * E + (tx << 3)]     = st0;
        *(float4*)&outL[t * E + (tx << 3) + 4] = st1;

        // top-8 on fp64 LOGITS (value desc, index asc) == jax.lax.top_k order
        double v[8];
#pragma unroll
        for (int j = 0; j < 8; ++j) v[j] = acc[i][j];

        float pk[K]; int ik[K]; float tsum = 0.f;
#pragma unroll
        for (int r = 0; r < K; ++r) {
            double bv = -1.0e300; int bi = 0x7fffffff;
#pragma unroll
            for (int j = 0; j < 8; ++j) {
                const int idx = (tx << 3) + j;
                const bool better = (v[j] > bv) || (v[j] == bv && idx < bi);
                bv = better ? v[j] : bv;
                bi = better ? idx : bi;
            }
#pragma unroll
            for (int mask = 1; mask <= 8; mask <<= 1) {
                const double ov = __shfl_xor(bv, mask, 64);
                const int    oi = __shfl_xor(bi, mask, 64);
                const bool better = (ov > bv) || (ov == bv && oi < bi);
                bv = better ? ov : bv;
                bi = better ? oi : bi;
            }
            const float pw = __expf((float)(bv - m)) * inv;
            pk[r] = pw; ik[r] = bi; tsum += pw;
            if ((bi >> 3) == tx) v[bi & 7] = -1.0e300;
        }

        if (tx == 0) {
            const float rinv = 1.f / tsum;
#pragma unroll
            for (int r = 0; r < K; ++r) {
                outWt[t * K + r] = pk[r] * rinv;
                outId[t * K + r] = (float)ik[r];
            }
        }
    }
}

extern "C" void kernel_launch(void* const* d_in, const int* in_sizes, int n_in,
                              void* d_out, int out_size, void* d_ws, size_t ws_size,
                              hipStream_t stream)
{
    const float* X = (const float*)d_in[0];
    const float* W = (const float*)d_in[1];
    float* out = (float*)d_out;
    router_fused<<<dim3(T / BM), dim3(256), 0, stream>>>(X, W, out);
}